// Round 5
// baseline (340.593 us; speedup 1.0000x reference)
//
#include <hip/hip_runtime.h>
#include <hip/hip_bf16.h>

typedef __attribute__((ext_vector_type(8))) short s16x8;
typedef __attribute__((ext_vector_type(4))) float f32x4;

#define BATCH 8
#define NPIX  4096
#define CCH   256
#define RCH   32
#define KVT   64
#define NT    (NPIX / KVT)
#define THR   8.0f

__device__ __forceinline__ unsigned short f2bf(float f) {
  __hip_bfloat16 h = __float2bfloat16(f);
  return __builtin_bit_cast(unsigned short, h);
}

__device__ __forceinline__ unsigned int pack_bf16(float lo, float hi) {
  return (unsigned int)f2bf(lo) | ((unsigned int)f2bf(hi) << 16);
}

// ---------------------------------------------------------------------------
// Kernel 0: cast x -> bf16; build wqk^T (64x256) and wv^T (256x256) in bf16.
// ---------------------------------------------------------------------------
__global__ void prep_kernel(const float* __restrict__ x,
                            const float* __restrict__ wq,
                            const float* __restrict__ wk,
                            const float* __restrict__ wv,
                            unsigned short* __restrict__ xb,
                            unsigned short* __restrict__ wqkT,
                            unsigned short* __restrict__ wvT) {
  int stride = gridDim.x * blockDim.x;
  int i0 = blockIdx.x * blockDim.x + threadIdx.x;
  const int nx4 = BATCH * NPIX * CCH / 4;
  for (int i = i0; i < nx4; i += stride) {
    float4 v = reinterpret_cast<const float4*>(x)[i];
    ushort4 o;
    o.x = f2bf(v.x); o.y = f2bf(v.y); o.z = f2bf(v.z); o.w = f2bf(v.w);
    reinterpret_cast<ushort4*>(xb)[i] = o;
  }
  for (int i = i0; i < 64 * CCH; i += stride) {
    int d = i >> 8, c = i & 255;
    float v = (d < RCH) ? wq[c * RCH + d] : wk[c * RCH + (d - RCH)];
    wqkT[i] = f2bf(v);
  }
  for (int i = i0; i < CCH * CCH; i += stride) {
    int d = i >> 8, c = i & 255;
    wvT[i] = f2bf(wv[c * CCH + d]);
  }
}

// ---------------------------------------------------------------------------
// Kernel 1: q,k projection with relu. rows flat over B*N; 64 cols = 32q+32k.
// ---------------------------------------------------------------------------
__global__ void qk_proj_kernel(const unsigned short* __restrict__ xb,
                               const unsigned short* __restrict__ wqkT,
                               const float* __restrict__ bq,
                               const float* __restrict__ bk,
                               unsigned short* __restrict__ qb,
                               unsigned short* __restrict__ kb) {
  int t = threadIdx.x;
  int w = t >> 6, l = t & 63, g = l >> 4, lc = l & 15;
  int row0 = blockIdx.x * 64 + w * 16;
  f32x4 zero = {0.f, 0.f, 0.f, 0.f};
  f32x4 acc[4];
  for (int ct = 0; ct < 4; ++ct) acc[ct] = zero;
  for (int ks = 0; ks < 8; ++ks) {
    s16x8 a = *reinterpret_cast<const s16x8*>(
        xb + (size_t)(row0 + lc) * CCH + ks * 32 + g * 8);
    for (int ct = 0; ct < 4; ++ct) {
      s16x8 bfr = *reinterpret_cast<const s16x8*>(
          wqkT + (size_t)(ct * 16 + lc) * CCH + ks * 32 + g * 8);
      acc[ct] = __builtin_amdgcn_mfma_f32_16x16x32_bf16(a, bfr, acc[ct], 0, 0, 0);
    }
  }
  for (int ct = 0; ct < 4; ++ct) {
    int col = ct * 16 + lc;
    float bias = (col < RCH) ? bq[col] : bk[col - RCH];
    for (int r = 0; r < 4; ++r) {
      int row = row0 + 4 * g + r;
      float v = fmaxf(acc[ct][r] + bias, 0.f);
      if (col < RCH) qb[(size_t)row * RCH + col] = f2bf(v);
      else           kb[(size_t)row * RCH + (col - RCH)] = f2bf(v);
    }
  }
}

// ---------------------------------------------------------------------------
// Kernel 2: v projection, stored transposed: vT[b][d][n]
// ---------------------------------------------------------------------------
__global__ void v_proj_kernel(const unsigned short* __restrict__ xb,
                              const unsigned short* __restrict__ wvT,
                              const float* __restrict__ bv,
                              unsigned short* __restrict__ vT) {
  int t = threadIdx.x;
  int w = t >> 6, l = t & 63, g = l >> 4, lc = l & 15;
  int idx = blockIdx.x;
  int b = idx & 7; idx >>= 3;
  int dt = idx & 3; int nt = idx >> 2;
  int d0 = dt * 64 + w * 16;
  int n0 = nt * 64;
  f32x4 zero = {0.f, 0.f, 0.f, 0.f};
  f32x4 acc[4];
  for (int ct = 0; ct < 4; ++ct) acc[ct] = zero;
  for (int ks = 0; ks < 8; ++ks) {
    s16x8 a = *reinterpret_cast<const s16x8*>(
        wvT + (size_t)(d0 + lc) * CCH + ks * 32 + g * 8);
    for (int ct = 0; ct < 4; ++ct) {
      s16x8 bfr = *reinterpret_cast<const s16x8*>(
          xb + ((size_t)b * NPIX + n0 + ct * 16 + lc) * CCH + ks * 32 + g * 8);
      acc[ct] = __builtin_amdgcn_mfma_f32_16x16x32_bf16(a, bfr, acc[ct], 0, 0, 0);
    }
  }
  for (int ct = 0; ct < 4; ++ct) {
    for (int r = 0; r < 4; ++r) {
      int d = d0 + 4 * g + r;
      int n = n0 + ct * 16 + lc;
      vT[((size_t)b * CCH + d) * NPIX + n] = f2bf(acc[ct][r] + bv[d]);
    }
  }
}

// ---------------------------------------------------------------------------
// Kernel 3: flash attention + residual. Producer/consumer wave split.
// Block = 1 batch x 32 queries, 6 waves (384 thr), grid 1024 (4 blocks/CU).
//   waves 0-1 (producer): QK^T (S^T via mfma(K,Q)), softmax, P -> LDS.
//   waves 2-5 (consumer): rescale O, P.V for their 64-channel slice.
// P double-buffered + XOR swizzle; ONE barrier per tile; defer-max (THR=8)
// with DEFERRED cross-lane max reduce + per-lane partial lsum (reduced once
// at the end). setprio(1) around consumer MFMA clusters.
// ---------------------------------------------------------------------------
__global__ __launch_bounds__(384, 6)
void attn_kernel(const unsigned short* __restrict__ qb,
                 const unsigned short* __restrict__ kb,
                 const unsigned short* __restrict__ vT,
                 const float* __restrict__ x,
                 float* __restrict__ out) {
  __shared__ __attribute__((aligned(16))) unsigned short Plds[2][32 * 64];
  __shared__ __attribute__((aligned(16))) float scaleArr[2][32];
  __shared__ __attribute__((aligned(16))) int flags[2][2];
  __shared__ __attribute__((aligned(16))) float lsumArr[32];

  int b = blockIdx.x & 7;          // batch == XCD -> vT/K/Q L2-resident
  int qt = blockIdx.x >> 3;        // 0..127
  int t = threadIdx.x;
  int w = t >> 6, l = t & 63, g = l >> 4, lc = l & 15;
  const size_t bN = (size_t)b * NPIX;
  f32x4 zero = {0.f, 0.f, 0.f, 0.f};

  if (w < 2) {
    // ================= producer =================
    int qrow = qt * 32 + w * 16 + lc;
    s16x8 qfrag = *reinterpret_cast<const s16x8*>(qb + (bN + qrow) * RCH + g * 8);
    const unsigned short* kbase = kb + bN * RCH;
    float m = -1e30f, lsum = 0.f;

    s16x8 kf[4];
    for (int ct = 0; ct < 4; ++ct)
      kf[ct] = *reinterpret_cast<const s16x8*>(
          kbase + (size_t)(ct * 16 + lc) * RCH + g * 8);

    for (int tix = 0; tix < NT; ++tix) {
      int p = tix & 1;

      f32x4 s[4];
      for (int ct = 0; ct < 4; ++ct)
        s[ct] = __builtin_amdgcn_mfma_f32_16x16x32_bf16(kf[ct], qfrag, zero, 0, 0, 0);

      // prefetch next K tile (wraps harmlessly on last iter)
      int tn = (tix + 1) & (NT - 1);
      for (int ct = 0; ct < 4; ++ct)
        kf[ct] = *reinterpret_cast<const s16x8*>(
            kbase + (size_t)(tn * KVT + ct * 16 + lc) * RCH + g * 8);

      // local max over this lane's 16 keys
      float pmax = s[0][0];
      for (int ct = 0; ct < 4; ++ct)
        for (int r = 0; r < 4; ++r) pmax = fmaxf(pmax, s[ct][r]);

      // deferred-max: only reduce + rescale when some lane's local max grew
      float sc = 1.f;
      int resc = !__all(pmax - m <= THR);
      if (resc) {
        pmax = fmaxf(pmax, __shfl_xor(pmax, 16));
        pmax = fmaxf(pmax, __shfl_xor(pmax, 32));
        float mnew = fmaxf(m, pmax);
        sc = __expf(m - mnew);
        m = mnew;
      }

      // exps + per-lane partial sum (sc is wave-uniform -> partials stay
      // consistent; reduced across lane copies once after the loop)
      float psum = 0.f;
      unsigned int pk[4][2];
      for (int ct = 0; ct < 4; ++ct) {
        float p0 = __expf(s[ct][0] - m);
        float p1 = __expf(s[ct][1] - m);
        float p2 = __expf(s[ct][2] - m);
        float p3 = __expf(s[ct][3] - m);
        psum += (p0 + p1) + (p2 + p3);
        pk[ct][0] = pack_bf16(p0, p1);
        pk[ct][1] = pack_bf16(p2, p3);
      }
      lsum = lsum * sc + psum;

      // write P[q_local][key_local] bf16, XOR-swizzled rows of 128B
      {
        int row = w * 16 + lc;
        unsigned int swz = (row & 7) << 4;
        char* base = (char*)&Plds[p][0] + row * 128;
        for (int ct = 0; ct < 4; ++ct) {
          unsigned long long v =
              ((unsigned long long)pk[ct][1] << 32) | pk[ct][0];
          *reinterpret_cast<unsigned long long*>(
              base + (((unsigned)(32 * ct + 8 * g)) ^ swz)) = v;
        }
      }
      if (l < 16) scaleArr[p][w * 16 + l] = sc;
      if (l == 0) flags[p][w] = resc;

      __syncthreads();
    }

    // final cross-lane lsum reduce (the 4 copies of query lc)
    lsum += __shfl_xor(lsum, 16);
    lsum += __shfl_xor(lsum, 32);
    if (l < 16) lsumArr[w * 16 + l] = lsum;
    __syncthreads();
  } else {
    // ================= consumer =================
    int wc = w - 2;                      // channel quarter [64wc, 64wc+64)
    const unsigned short* vbase = vT + (size_t)b * CCH * NPIX;
    int voff[4];
    for (int cc = 0; cc < 4; ++cc)
      voff[cc] = (64 * wc + cc * 16 + lc) * NPIX;

    f32x4 o[2][4];
    for (int qc = 0; qc < 2; ++qc)
      for (int cc = 0; cc < 4; ++cc) o[qc][cc] = zero;

    for (int tix = 0; tix < NT; ++tix) {
      int p = tix & 1;
      int kv0 = tix * KVT;

      // V half-0 loads issued before the barrier (read-only global, no race)
      s16x8 vb0[4];
      for (int cc = 0; cc < 4; ++cc)
        vb0[cc] = *reinterpret_cast<const s16x8*>(
            vbase + (size_t)voff[cc] + kv0 + 8 * g);

      __syncthreads();

      int2 fl = *reinterpret_cast<const int2*>(&flags[p][0]);
      if (fl.x | fl.y) {
        for (int qc = 0; qc < 2; ++qc) {
          f32x4 s4 = *reinterpret_cast<const f32x4*>(&scaleArr[p][qc * 16 + 4 * g]);
          for (int cc = 0; cc < 4; ++cc)
            for (int r = 0; r < 4; ++r) o[qc][cc][r] *= s4[r];
        }
      }

      s16x8 pa[2];
      for (int qc = 0; qc < 2; ++qc) {
        int row = qc * 16 + lc;
        unsigned int swz = (row & 7) << 4;
        pa[qc] = *reinterpret_cast<const s16x8*>(
            (char*)&Plds[p][0] + row * 128 + (((unsigned)(16 * g)) ^ swz));
      }
      // V half-1 loads issued before half-0 MFMAs
      s16x8 vb1[4];
      for (int cc = 0; cc < 4; ++cc)
        vb1[cc] = *reinterpret_cast<const s16x8*>(
            vbase + (size_t)voff[cc] + kv0 + 32 + 8 * g);

      __builtin_amdgcn_s_setprio(1);
      for (int cc = 0; cc < 4; ++cc)
        for (int qc = 0; qc < 2; ++qc)
          o[qc][cc] = __builtin_amdgcn_mfma_f32_16x16x32_bf16(
              pa[qc], vb0[cc], o[qc][cc], 0, 0, 0);
      __builtin_amdgcn_s_setprio(0);

      for (int qc = 0; qc < 2; ++qc) {
        int row = qc * 16 + lc;
        unsigned int swz = (row & 7) << 4;
        pa[qc] = *reinterpret_cast<const s16x8*>(
            (char*)&Plds[p][0] + row * 128 + (((unsigned)(64 + 16 * g)) ^ swz));
      }
      __builtin_amdgcn_s_setprio(1);
      for (int cc = 0; cc < 4; ++cc)
        for (int qc = 0; qc < 2; ++qc)
          o[qc][cc] = __builtin_amdgcn_mfma_f32_16x16x32_bf16(
              pa[qc], vb1[cc], o[qc][cc], 0, 0, 0);
      __builtin_amdgcn_s_setprio(0);
    }

    __syncthreads();   // lsumArr ready

    for (int qc = 0; qc < 2; ++qc) {
      f32x4 l4 = *reinterpret_cast<const f32x4*>(&lsumArr[qc * 16 + 4 * g]);
      f32x4 rl;
      for (int r = 0; r < 4; ++r) rl[r] = 1.0f / l4[r];
      for (int cc = 0; cc < 4; ++cc) {
        for (int r = 0; r < 4; ++r) {
          size_t row = bN + qt * 32 + qc * 16 + 4 * g + r;
          size_t idx = row * CCH + 64 * wc + cc * 16 + lc;
          out[idx] = o[qc][cc][r] * rl[r] + x[idx];
        }
      }
    }
  }
}

// ---------------------------------------------------------------------------
extern "C" void kernel_launch(void* const* d_in, const int* in_sizes, int n_in,
                              void* d_out, int out_size, void* d_ws, size_t ws_size,
                              hipStream_t stream) {
  const float* x  = (const float*)d_in[0];
  const float* wq = (const float*)d_in[1];
  const float* bq = (const float*)d_in[2];
  const float* wk = (const float*)d_in[3];
  const float* bk = (const float*)d_in[4];
  const float* wv = (const float*)d_in[5];
  const float* bv = (const float*)d_in[6];
  float* out = (float*)d_out;

  unsigned short* ws   = (unsigned short*)d_ws;
  unsigned short* qb   = ws;                   // 8*4096*32  = 1,048,576
  unsigned short* kb   = qb + 1048576;         // 1,048,576
  unsigned short* vT   = kb + 1048576;         // 8*256*4096 = 8,388,608
  unsigned short* xb   = vT + 8388608;         // 8,388,608
  unsigned short* wqkT = xb + 8388608;         // 64*256 = 16,384
  unsigned short* wvT  = wqkT + 16384;         // 256*256 = 65,536

  prep_kernel<<<dim3(2048), dim3(256), 0, stream>>>(x, wq, wk, wv, xb, wqkT, wvT);
  qk_proj_kernel<<<dim3(512), dim3(256), 0, stream>>>(xb, wqkT, bq, bk, qb, kb);
  v_proj_kernel<<<dim3(2048), dim3(256), 0, stream>>>(xb, wvT, bv, vT);
  attn_kernel<<<dim3(1024), dim3(384), 0, stream>>>(qb, kb, vT, x, out);
}

// Round 6
// 213.582 us; speedup vs baseline: 1.5947x; 1.5947x over previous
//
#include <hip/hip_runtime.h>
#include <hip/hip_bf16.h>

typedef __attribute__((ext_vector_type(8))) short s16x8;
typedef __attribute__((ext_vector_type(4))) float f32x4;

#define BATCH 8
#define NPIX  4096
#define CCH   256
#define RCH   32
#define KVT   128
#define NT    (NPIX / KVT)
#define THR   8.0f

__device__ __forceinline__ unsigned short f2bf(float f) {
  __hip_bfloat16 h = __float2bfloat16(f);
  return __builtin_bit_cast(unsigned short, h);
}

__device__ __forceinline__ unsigned int pack_bf16(float lo, float hi) {
  return (unsigned int)f2bf(lo) | ((unsigned int)f2bf(hi) << 16);
}

// ---------------------------------------------------------------------------
// Kernel 0: cast x -> bf16; build wqk^T (64x256) and wv^T (256x256) in bf16.
// ---------------------------------------------------------------------------
__global__ void prep_kernel(const float* __restrict__ x,
                            const float* __restrict__ wq,
                            const float* __restrict__ wk,
                            const float* __restrict__ wv,
                            unsigned short* __restrict__ xb,
                            unsigned short* __restrict__ wqkT,
                            unsigned short* __restrict__ wvT) {
  int stride = gridDim.x * blockDim.x;
  int i0 = blockIdx.x * blockDim.x + threadIdx.x;
  const int nx4 = BATCH * NPIX * CCH / 4;
  for (int i = i0; i < nx4; i += stride) {
    float4 v = reinterpret_cast<const float4*>(x)[i];
    ushort4 o;
    o.x = f2bf(v.x); o.y = f2bf(v.y); o.z = f2bf(v.z); o.w = f2bf(v.w);
    reinterpret_cast<ushort4*>(xb)[i] = o;
  }
  for (int i = i0; i < 64 * CCH; i += stride) {
    int d = i >> 8, c = i & 255;
    float v = (d < RCH) ? wq[c * RCH + d] : wk[c * RCH + (d - RCH)];
    wqkT[i] = f2bf(v);
  }
  for (int i = i0; i < CCH * CCH; i += stride) {
    int d = i >> 8, c = i & 255;
    wvT[i] = f2bf(wv[c * CCH + d]);
  }
}

// ---------------------------------------------------------------------------
// Kernel 1: q,k projection with relu. rows flat over B*N; 64 cols = 32q+32k.
// ---------------------------------------------------------------------------
__global__ void qk_proj_kernel(const unsigned short* __restrict__ xb,
                               const unsigned short* __restrict__ wqkT,
                               const float* __restrict__ bq,
                               const float* __restrict__ bk,
                               unsigned short* __restrict__ qb,
                               unsigned short* __restrict__ kb) {
  int t = threadIdx.x;
  int w = t >> 6, l = t & 63, g = l >> 4, lc = l & 15;
  int row0 = blockIdx.x * 64 + w * 16;
  f32x4 zero = {0.f, 0.f, 0.f, 0.f};
  f32x4 acc[4];
  for (int ct = 0; ct < 4; ++ct) acc[ct] = zero;
  for (int ks = 0; ks < 8; ++ks) {
    s16x8 a = *reinterpret_cast<const s16x8*>(
        xb + (size_t)(row0 + lc) * CCH + ks * 32 + g * 8);
    for (int ct = 0; ct < 4; ++ct) {
      s16x8 bfr = *reinterpret_cast<const s16x8*>(
          wqkT + (size_t)(ct * 16 + lc) * CCH + ks * 32 + g * 8);
      acc[ct] = __builtin_amdgcn_mfma_f32_16x16x32_bf16(a, bfr, acc[ct], 0, 0, 0);
    }
  }
  for (int ct = 0; ct < 4; ++ct) {
    int col = ct * 16 + lc;
    float bias = (col < RCH) ? bq[col] : bk[col - RCH];
    for (int r = 0; r < 4; ++r) {
      int row = row0 + 4 * g + r;
      float v = fmaxf(acc[ct][r] + bias, 0.f);
      if (col < RCH) qb[(size_t)row * RCH + col] = f2bf(v);
      else           kb[(size_t)row * RCH + (col - RCH)] = f2bf(v);
    }
  }
}

// ---------------------------------------------------------------------------
// Kernel 2: v projection, stored transposed: vT[b][d][n]
// ---------------------------------------------------------------------------
__global__ void v_proj_kernel(const unsigned short* __restrict__ xb,
                              const unsigned short* __restrict__ wvT,
                              const float* __restrict__ bv,
                              unsigned short* __restrict__ vT) {
  int t = threadIdx.x;
  int w = t >> 6, l = t & 63, g = l >> 4, lc = l & 15;
  int idx = blockIdx.x;
  int b = idx & 7; idx >>= 3;
  int dt = idx & 3; int nt = idx >> 2;
  int d0 = dt * 64 + w * 16;
  int n0 = nt * 64;
  f32x4 zero = {0.f, 0.f, 0.f, 0.f};
  f32x4 acc[4];
  for (int ct = 0; ct < 4; ++ct) acc[ct] = zero;
  for (int ks = 0; ks < 8; ++ks) {
    s16x8 a = *reinterpret_cast<const s16x8*>(
        wvT + (size_t)(d0 + lc) * CCH + ks * 32 + g * 8);
    for (int ct = 0; ct < 4; ++ct) {
      s16x8 bfr = *reinterpret_cast<const s16x8*>(
          xb + ((size_t)b * NPIX + n0 + ct * 16 + lc) * CCH + ks * 32 + g * 8);
      acc[ct] = __builtin_amdgcn_mfma_f32_16x16x32_bf16(a, bfr, acc[ct], 0, 0, 0);
    }
  }
  for (int ct = 0; ct < 4; ++ct) {
    for (int r = 0; r < 4; ++r) {
      int d = d0 + 4 * g + r;
      int n = n0 + ct * 16 + lc;
      vT[((size_t)b * CCH + d) * NPIX + n] = f2bf(acc[ct][r] + bv[d]);
    }
  }
}

// ---------------------------------------------------------------------------
// Kernel 3: flash attention + residual. Producer/consumer wave split.
// Block = 1 batch x 64 queries, 8 waves (512 thr), grid 512.
//   waves 0-3 (producer): QK^T over 128-key tile, softmax, P -> LDS.
//   waves 4-7 (consumer): rescale O, P.V (4 chunks of 32 keys).
// KVT=128 -> 32 barrier rounds (half of R4). P dbuf + XOR swizzle;
// defer-max (THR=8) with deferred cross-lane reduce + per-lane partial lsum.
// setprio(1) around the producer critical chain.
// ---------------------------------------------------------------------------
__global__ __launch_bounds__(512, 4)
void attn_kernel(const unsigned short* __restrict__ qb,
                 const unsigned short* __restrict__ kb,
                 const unsigned short* __restrict__ vT,
                 const float* __restrict__ x,
                 float* __restrict__ out) {
  __shared__ __attribute__((aligned(16))) unsigned short Plds[2][64 * 128];
  __shared__ __attribute__((aligned(16))) float scaleArr[2][64];
  __shared__ __attribute__((aligned(16))) int flags[2][4];
  __shared__ __attribute__((aligned(16))) float lsumArr[64];

  int b = blockIdx.x & 7;          // batch == XCD -> vT/K/Q L2-resident
  int qt = blockIdx.x >> 3;        // 0..63
  int t = threadIdx.x;
  int w = t >> 6, l = t & 63, g = l >> 4, lc = l & 15;
  const size_t bN = (size_t)b * NPIX;
  f32x4 zero = {0.f, 0.f, 0.f, 0.f};

  if (w < 4) {
    // ================= producer =================
    int qrow = qt * 64 + w * 16 + lc;
    s16x8 qfrag = *reinterpret_cast<const s16x8*>(qb + (bN + qrow) * RCH + g * 8);
    const unsigned short* kbase = kb + bN * RCH;
    float m = -1e30f, lsum = 0.f;

    s16x8 kf[8];
    for (int ct = 0; ct < 8; ++ct)
      kf[ct] = *reinterpret_cast<const s16x8*>(
          kbase + (size_t)(ct * 16 + lc) * RCH + g * 8);

    for (int tix = 0; tix < NT; ++tix) {
      int p = tix & 1;

      __builtin_amdgcn_s_setprio(1);
      f32x4 s[8];
      for (int ct = 0; ct < 8; ++ct)
        s[ct] = __builtin_amdgcn_mfma_f32_16x16x32_bf16(kf[ct], qfrag, zero, 0, 0, 0);

      // prefetch next K tile (wraps harmlessly on last iter)
      int tn = (tix + 1) & (NT - 1);
      for (int ct = 0; ct < 8; ++ct)
        kf[ct] = *reinterpret_cast<const s16x8*>(
            kbase + (size_t)(tn * KVT + ct * 16 + lc) * RCH + g * 8);

      // local max over this lane's 32 keys
      float pmax = s[0][0];
      for (int ct = 0; ct < 8; ++ct)
        for (int r = 0; r < 4; ++r) pmax = fmaxf(pmax, s[ct][r]);

      // deferred-max: reduce + rescale only when some lane's local max grew
      float sc = 1.f;
      int resc = !__all(pmax - m <= THR);
      if (resc) {
        pmax = fmaxf(pmax, __shfl_xor(pmax, 16));
        pmax = fmaxf(pmax, __shfl_xor(pmax, 32));
        float mnew = fmaxf(m, pmax);
        sc = __expf(m - mnew);
        m = mnew;
      }

      // exps + per-lane partial sum (sc wave-uniform -> consistent partials)
      float psum = 0.f;
      unsigned int pk[8][2];
      for (int ct = 0; ct < 8; ++ct) {
        float p0 = __expf(s[ct][0] - m);
        float p1 = __expf(s[ct][1] - m);
        float p2 = __expf(s[ct][2] - m);
        float p3 = __expf(s[ct][3] - m);
        psum += (p0 + p1) + (p2 + p3);
        pk[ct][0] = pack_bf16(p0, p1);
        pk[ct][1] = pack_bf16(p2, p3);
      }
      lsum = lsum * sc + psum;

      // write P[q_local][key_local] bf16, XOR-swizzled rows of 256B
      {
        int row = w * 16 + lc;
        unsigned int swz = (row & 7) << 4;
        char* base = (char*)&Plds[p][0] + row * 256;
        for (int ct = 0; ct < 8; ++ct) {
          unsigned long long v =
              ((unsigned long long)pk[ct][1] << 32) | pk[ct][0];
          *reinterpret_cast<unsigned long long*>(
              base + (((unsigned)(32 * ct + 8 * g)) ^ swz)) = v;
        }
      }
      __builtin_amdgcn_s_setprio(0);
      if (l < 16) scaleArr[p][w * 16 + l] = sc;
      if (l == 0) flags[p][w] = resc;

      __syncthreads();
    }

    // final cross-lane lsum reduce (the 4 copies of query lc)
    lsum += __shfl_xor(lsum, 16);
    lsum += __shfl_xor(lsum, 32);
    if (l < 16) lsumArr[w * 16 + l] = lsum;
    __syncthreads();
  } else {
    // ================= consumer =================
    int wc = w - 4;                      // channel quarter [64wc, 64wc+64)
    const unsigned short* vbase = vT + (size_t)b * CCH * NPIX;
    int voff[4];
    for (int cc = 0; cc < 4; ++cc)
      voff[cc] = (64 * wc + cc * 16 + lc) * NPIX;

    f32x4 o[4][4];
    for (int qc = 0; qc < 4; ++qc)
      for (int cc = 0; cc < 4; ++cc) o[qc][cc] = zero;

    for (int tix = 0; tix < NT; ++tix) {
      int p = tix & 1;
      int kv0 = tix * KVT;

      // chunk-0 V loads issued before the barrier (read-only global, no race)
      s16x8 vb[4];
      for (int cc = 0; cc < 4; ++cc)
        vb[cc] = *reinterpret_cast<const s16x8*>(
            vbase + (size_t)voff[cc] + kv0 + 8 * g);

      __syncthreads();

      int4 fl = *reinterpret_cast<const int4*>(&flags[p][0]);
      if (fl.x | fl.y | fl.z | fl.w) {
        for (int qc = 0; qc < 4; ++qc) {
          f32x4 s4 = *reinterpret_cast<const f32x4*>(&scaleArr[p][qc * 16 + 4 * g]);
          for (int cc = 0; cc < 4; ++cc)
            for (int r = 0; r < 4; ++r) o[qc][cc][r] *= s4[r];
        }
      }

      // 4 chunks of 32 keys; P reads swizzled; V loads per chunk.
      #pragma unroll
      for (int ks = 0; ks < 4; ++ks) {
        s16x8 pa[4];
        for (int qc = 0; qc < 4; ++qc) {
          int row = qc * 16 + lc;
          unsigned int swz = (row & 7) << 4;
          pa[qc] = *reinterpret_cast<const s16x8*>(
              (char*)&Plds[p][0] + row * 256 +
              (((unsigned)(64 * ks + 16 * g)) ^ swz));
        }
        // next chunk's V loads issued before this chunk's MFMAs
        s16x8 vn[4];
        if (ks < 3) {
          for (int cc = 0; cc < 4; ++cc)
            vn[cc] = *reinterpret_cast<const s16x8*>(
                vbase + (size_t)voff[cc] + kv0 + 32 * (ks + 1) + 8 * g);
        }
        for (int cc = 0; cc < 4; ++cc)
          for (int qc = 0; qc < 4; ++qc)
            o[qc][cc] = __builtin_amdgcn_mfma_f32_16x16x32_bf16(
                pa[qc], vb[cc], o[qc][cc], 0, 0, 0);
        if (ks < 3)
          for (int cc = 0; cc < 4; ++cc) vb[cc] = vn[cc];
      }
    }

    __syncthreads();   // lsumArr ready

    for (int qc = 0; qc < 4; ++qc) {
      f32x4 l4 = *reinterpret_cast<const f32x4*>(&lsumArr[qc * 16 + 4 * g]);
      f32x4 rl;
      for (int r = 0; r < 4; ++r) rl[r] = 1.0f / l4[r];
      for (int cc = 0; cc < 4; ++cc) {
        for (int r = 0; r < 4; ++r) {
          size_t row = bN + qt * 64 + qc * 16 + 4 * g + r;
          size_t idx = row * CCH + 64 * wc + cc * 16 + lc;
          out[idx] = o[qc][cc][r] * rl[r] + x[idx];
        }
      }
    }
  }
}

// ---------------------------------------------------------------------------
extern "C" void kernel_launch(void* const* d_in, const int* in_sizes, int n_in,
                              void* d_out, int out_size, void* d_ws, size_t ws_size,
                              hipStream_t stream) {
  const float* x  = (const float*)d_in[0];
  const float* wq = (const float*)d_in[1];
  const float* bq = (const float*)d_in[2];
  const float* wk = (const float*)d_in[3];
  const float* bk = (const float*)d_in[4];
  const float* wv = (const float*)d_in[5];
  const float* bv = (const float*)d_in[6];
  float* out = (float*)d_out;

  unsigned short* ws   = (unsigned short*)d_ws;
  unsigned short* qb   = ws;                   // 8*4096*32  = 1,048,576
  unsigned short* kb   = qb + 1048576;         // 1,048,576
  unsigned short* vT   = kb + 1048576;         // 8*256*4096 = 8,388,608
  unsigned short* xb   = vT + 8388608;         // 8,388,608
  unsigned short* wqkT = xb + 8388608;         // 64*256 = 16,384
  unsigned short* wvT  = wqkT + 16384;         // 256*256 = 65,536

  prep_kernel<<<dim3(2048), dim3(256), 0, stream>>>(x, wq, wk, wv, xb, wqkT, wvT);
  qk_proj_kernel<<<dim3(512), dim3(256), 0, stream>>>(xb, wqkT, bq, bk, qb, kb);
  v_proj_kernel<<<dim3(2048), dim3(256), 0, stream>>>(xb, wvT, bv, vT);
  attn_kernel<<<dim3(512), dim3(512), 0, stream>>>(qb, kb, vT, x, out);
}

// Round 7
// 173.991 us; speedup vs baseline: 1.9575x; 1.2275x over previous
//
#include <hip/hip_runtime.h>
#include <hip/hip_bf16.h>

typedef __attribute__((ext_vector_type(8))) short s16x8;
typedef __attribute__((ext_vector_type(4))) float f32x4;
typedef __attribute__((ext_vector_type(4))) unsigned int u32x4;

#define BATCH 8
#define NPIX  4096
#define CCH   256
#define RCH   32
#define KVT   64
#define NT    (NPIX / KVT)
#define THR   8.0f

__device__ __forceinline__ unsigned short f2bf(float f) {
  __hip_bfloat16 h = __float2bfloat16(f);
  return __builtin_bit_cast(unsigned short, h);
}

__device__ __forceinline__ unsigned int pack_bf16(float lo, float hi) {
  return (unsigned int)f2bf(lo) | ((unsigned int)f2bf(hi) << 16);
}

// ---------------------------------------------------------------------------
// Kernel 0: cast x -> bf16; build wqk^T (64x256) and wv^T (256x256) in bf16.
// ---------------------------------------------------------------------------
__global__ void prep_kernel(const float* __restrict__ x,
                            const float* __restrict__ wq,
                            const float* __restrict__ wk,
                            const float* __restrict__ wv,
                            unsigned short* __restrict__ xb,
                            unsigned short* __restrict__ wqkT,
                            unsigned short* __restrict__ wvT) {
  int stride = gridDim.x * blockDim.x;
  int i0 = blockIdx.x * blockDim.x + threadIdx.x;
  const int nx4 = BATCH * NPIX * CCH / 4;
  for (int i = i0; i < nx4; i += stride) {
    float4 v = reinterpret_cast<const float4*>(x)[i];
    ushort4 o;
    o.x = f2bf(v.x); o.y = f2bf(v.y); o.z = f2bf(v.z); o.w = f2bf(v.w);
    reinterpret_cast<ushort4*>(xb)[i] = o;
  }
  for (int i = i0; i < 64 * CCH; i += stride) {
    int d = i >> 8, c = i & 255;
    float v = (d < RCH) ? wq[c * RCH + d] : wk[c * RCH + (d - RCH)];
    wqkT[i] = f2bf(v);
  }
  for (int i = i0; i < CCH * CCH; i += stride) {
    int d = i >> 8, c = i & 255;
    wvT[i] = f2bf(wv[c * CCH + d]);
  }
}

// ---------------------------------------------------------------------------
// Kernel 1: q,k projection with relu. rows flat over B*N; 64 cols = 32q+32k.
// ---------------------------------------------------------------------------
__global__ void qk_proj_kernel(const unsigned short* __restrict__ xb,
                               const unsigned short* __restrict__ wqkT,
                               const float* __restrict__ bq,
                               const float* __restrict__ bk,
                               unsigned short* __restrict__ qb,
                               unsigned short* __restrict__ kb) {
  int t = threadIdx.x;
  int w = t >> 6, l = t & 63, g = l >> 4, lc = l & 15;
  int row0 = blockIdx.x * 64 + w * 16;
  f32x4 zero = {0.f, 0.f, 0.f, 0.f};
  f32x4 acc[4];
  for (int ct = 0; ct < 4; ++ct) acc[ct] = zero;
  for (int ks = 0; ks < 8; ++ks) {
    s16x8 a = *reinterpret_cast<const s16x8*>(
        xb + (size_t)(row0 + lc) * CCH + ks * 32 + g * 8);
    for (int ct = 0; ct < 4; ++ct) {
      s16x8 bfr = *reinterpret_cast<const s16x8*>(
          wqkT + (size_t)(ct * 16 + lc) * CCH + ks * 32 + g * 8);
      acc[ct] = __builtin_amdgcn_mfma_f32_16x16x32_bf16(a, bfr, acc[ct], 0, 0, 0);
    }
  }
  for (int ct = 0; ct < 4; ++ct) {
    int col = ct * 16 + lc;
    float bias = (col < RCH) ? bq[col] : bk[col - RCH];
    for (int r = 0; r < 4; ++r) {
      int row = row0 + 4 * g + r;
      float v = fmaxf(acc[ct][r] + bias, 0.f);
      if (col < RCH) qb[(size_t)row * RCH + col] = f2bf(v);
      else           kb[(size_t)row * RCH + (col - RCH)] = f2bf(v);
    }
  }
}

// ---------------------------------------------------------------------------
// Kernel 2: v projection, stored transposed: vT[b][d][n]
// ---------------------------------------------------------------------------
__global__ void v_proj_kernel(const unsigned short* __restrict__ xb,
                              const unsigned short* __restrict__ wvT,
                              const float* __restrict__ bv,
                              unsigned short* __restrict__ vT) {
  int t = threadIdx.x;
  int w = t >> 6, l = t & 63, g = l >> 4, lc = l & 15;
  int idx = blockIdx.x;
  int b = idx & 7; idx >>= 3;
  int dt = idx & 3; int nt = idx >> 2;
  int d0 = dt * 64 + w * 16;
  int n0 = nt * 64;
  f32x4 zero = {0.f, 0.f, 0.f, 0.f};
  f32x4 acc[4];
  for (int ct = 0; ct < 4; ++ct) acc[ct] = zero;
  for (int ks = 0; ks < 8; ++ks) {
    s16x8 a = *reinterpret_cast<const s16x8*>(
        wvT + (size_t)(d0 + lc) * CCH + ks * 32 + g * 8);
    for (int ct = 0; ct < 4; ++ct) {
      s16x8 bfr = *reinterpret_cast<const s16x8*>(
          xb + ((size_t)b * NPIX + n0 + ct * 16 + lc) * CCH + ks * 32 + g * 8);
      acc[ct] = __builtin_amdgcn_mfma_f32_16x16x32_bf16(a, bfr, acc[ct], 0, 0, 0);
    }
  }
  for (int ct = 0; ct < 4; ++ct) {
    for (int r = 0; r < 4; ++r) {
      int d = d0 + 4 * g + r;
      int n = n0 + ct * 16 + lc;
      vT[((size_t)b * CCH + d) * NPIX + n] = f2bf(acc[ct][r] + bv[d]);
    }
  }
}

// ---------------------------------------------------------------------------
// Kernel 3: flash attention + residual. SYMMETRIC waves, P in-register.
// Block = 1 batch x 64 queries, 4 waves (256 thr), grid 512 (2 blocks/CU).
// Each wave: 16 q (lane-col = lc), ALL 256 channels.
//   - K rows loaded PRE-PERMUTED so the swapped-QK output (S^T) lands
//     exactly in PV A-fragment order: no cross-lane exchange, no P-LDS.
//     krow(ct,lc) = 32*(ct>>1) + 8*(lc>>2) + 4*(ct&1) + (lc&3)
//     => lane (g,lc) reg (ct,r) holds key 32*(ct>>1)+8g+4*(ct&1)+r.
//   - V tile (256ch x 64 keys) staged in LDS, XOR-swizzled 16B granules
//     (both write & read sides), double-buffered, ONE barrier per tile.
//   - wave-global running max m (uniform) -> O-rescale is a scalar mul;
//     defer-max THR=8; per-lane partial lsum reduced once at the end.
// ---------------------------------------------------------------------------
__global__ __launch_bounds__(256, 2)
void attn_kernel(const unsigned short* __restrict__ qb,
                 const unsigned short* __restrict__ kb,
                 const unsigned short* __restrict__ vT,
                 const float* __restrict__ x,
                 float* __restrict__ out) {
  __shared__ __attribute__((aligned(16))) unsigned short Vlds[2][CCH * KVT];
  __shared__ float lsumLds[64];

  int b  = blockIdx.x & 7;         // batch == XCD -> vT/K/Q L2-resident
  int qt = blockIdx.x >> 3;        // 0..63
  int t  = threadIdx.x;
  int w = t >> 6, l = t & 63, g = l >> 4, lc = l & 15;
  const size_t bN = (size_t)b * NPIX;
  f32x4 zero = {0.f, 0.f, 0.f, 0.f};

  const unsigned short* kbase = kb + bN * RCH;
  const unsigned short* vbase = vT + (size_t)b * CCH * NPIX;

  // Q fragment (B-operand of QK): q = qt*64 + w*16 + lc, d = 8g..8g+7
  int qrow = qt * 64 + w * 16 + lc;
  s16x8 qfrag = *reinterpret_cast<const s16x8*>(qb + (bN + qrow) * RCH + g * 8);

  // ---- stage addressing (thread-constant): thread covers ch = t>>3 + 32i,
  //      granule gr = t&7 (8 keys x 16B). ----
  int chb = t >> 3, gr = t & 7;
  const unsigned short* vsrc0 = vbase + (size_t)chb * NPIX + gr * 8;
  int vdst0 = chb * 128 + ((gr * 16) ^ ((chb & 7) * 16));

  // ---- K permuted-row base ----
  int krb = 8 * (lc >> 2) + (lc & 3);
  const int cto[4] = {0, 4, 32, 36};

  // ---- PV read offsets ----
  int swz = (lc & 7) * 16;
  int vr0 = (g * 16) ^ swz;               // keys 0-31 granule
  int vr1 = ((64 + g * 16)) ^ swz;        // keys 32-63 granule

  f32x4 o[16];
  #pragma unroll
  for (int cc = 0; cc < 16; ++cc) o[cc] = zero;
  float m = -1e30f, lsum = 0.f;

  // ---- prologue: stage tile 0, load K tile 0 ----
  s16x8 kf[4];
  {
    s16x8 gv[8];
    #pragma unroll
    for (int i = 0; i < 8; ++i)
      gv[i] = *reinterpret_cast<const s16x8*>(vsrc0 + (size_t)i * 32 * NPIX);
    #pragma unroll
    for (int ct = 0; ct < 4; ++ct)
      kf[ct] = *reinterpret_cast<const s16x8*>(
          kbase + (size_t)(cto[ct] + krb) * RCH + g * 8);
    #pragma unroll
    for (int i = 0; i < 8; ++i)
      *reinterpret_cast<s16x8*>((char*)&Vlds[0][0] + vdst0 + i * 4096) = gv[i];
  }
  __syncthreads();

  for (int tix = 0; tix < NT; ++tix) {
    int p = tix & 1;
    int kv0 = tix * KVT;
    bool nx = (tix + 1) < NT;

    // issue next V-tile loads early (latency hides under QK+softmax)
    s16x8 gv[8];
    if (nx) {
      #pragma unroll
      for (int i = 0; i < 8; ++i)
        gv[i] = *reinterpret_cast<const s16x8*>(
            vsrc0 + kv0 + KVT + (size_t)i * 32 * NPIX);
    }

    // ---- QK^T: S^T in PV-ready key order ----
    f32x4 s[4];
    #pragma unroll
    for (int ct = 0; ct < 4; ++ct)
      s[ct] = __builtin_amdgcn_mfma_f32_16x16x32_bf16(kf[ct], qfrag, zero, 0, 0, 0);

    // prefetch next K tile
    if (nx) {
      #pragma unroll
      for (int ct = 0; ct < 4; ++ct)
        kf[ct] = *reinterpret_cast<const s16x8*>(
            kbase + (size_t)(kv0 + KVT + cto[ct] + krb) * RCH + g * 8);
    }

    // ---- softmax (wave-global max, deferred) ----
    float pmax = s[0][0];
    #pragma unroll
    for (int ct = 0; ct < 4; ++ct)
      #pragma unroll
      for (int r = 0; r < 4; ++r) pmax = fmaxf(pmax, s[ct][r]);

    float sc = 1.f;
    int resc = !__all(pmax - m <= THR);
    if (resc) {
      #pragma unroll
      for (int off = 1; off <= 32; off <<= 1)
        pmax = fmaxf(pmax, __shfl_xor(pmax, off));
      float mnew = fmaxf(m, pmax);
      sc = __expf(m - mnew);
      m = mnew;
    }

    float psum = 0.f;
    unsigned int pk[4][2];
    #pragma unroll
    for (int ct = 0; ct < 4; ++ct) {
      float p0 = __expf(s[ct][0] - m);
      float p1 = __expf(s[ct][1] - m);
      float p2 = __expf(s[ct][2] - m);
      float p3 = __expf(s[ct][3] - m);
      psum += (p0 + p1) + (p2 + p3);
      pk[ct][0] = pack_bf16(p0, p1);
      pk[ct][1] = pack_bf16(p2, p3);
    }
    lsum = lsum * sc + psum;

    // uniform O rescale (rare after warmup)
    if (resc) {
      #pragma unroll
      for (int cc = 0; cc < 16; ++cc)
        #pragma unroll
        for (int r = 0; r < 4; ++r) o[cc][r] *= sc;
    }

    // ---- write next V tile to the other buffer (loads have landed) ----
    if (nx) {
      #pragma unroll
      for (int i = 0; i < 8; ++i)
        *reinterpret_cast<s16x8*>((char*)&Vlds[p ^ 1][0] + vdst0 + i * 4096) = gv[i];
    }

    // ---- PV: A = in-register P, B = V from LDS ----
    u32x4 a0u = {pk[0][0], pk[0][1], pk[1][0], pk[1][1]};
    u32x4 a1u = {pk[2][0], pk[2][1], pk[3][0], pk[3][1]};
    s16x8 pa0 = __builtin_bit_cast(s16x8, a0u);
    s16x8 pa1 = __builtin_bit_cast(s16x8, a1u);
    const char* pb = (const char*)&Vlds[p][0] + lc * 128;
    #pragma unroll
    for (int cc = 0; cc < 16; ++cc) {
      s16x8 vb0 = *reinterpret_cast<const s16x8*>(pb + cc * 2048 + vr0);
      s16x8 vb1 = *reinterpret_cast<const s16x8*>(pb + cc * 2048 + vr1);
      o[cc] = __builtin_amdgcn_mfma_f32_16x16x32_bf16(pa0, vb0, o[cc], 0, 0, 0);
      o[cc] = __builtin_amdgcn_mfma_f32_16x16x32_bf16(pa1, vb1, o[cc], 0, 0, 0);
    }

    __syncthreads();
  }

  // ---- lsum: reduce the 4 g-copies, redistribute to output layout ----
  lsum += __shfl_xor(lsum, 16);
  lsum += __shfl_xor(lsum, 32);
  if (l < 16) lsumLds[w * 16 + l] = lsum;
  __syncthreads();

  f32x4 l4 = *reinterpret_cast<const f32x4*>(&lsumLds[w * 16 + 4 * g]);
  f32x4 rl;
  #pragma unroll
  for (int r = 0; r < 4; ++r) rl[r] = 1.0f / l4[r];

  // output: lane (g,lc) holds O[q = w*16 + 4g+r][ch = cc*16+lc]
  #pragma unroll
  for (int cc = 0; cc < 16; ++cc) {
    #pragma unroll
    for (int r = 0; r < 4; ++r) {
      size_t row = bN + qt * 64 + w * 16 + 4 * g + r;
      size_t idx = row * CCH + cc * 16 + lc;
      out[idx] = o[cc][r] * rl[r] + x[idx];
    }
  }
}

// ---------------------------------------------------------------------------
extern "C" void kernel_launch(void* const* d_in, const int* in_sizes, int n_in,
                              void* d_out, int out_size, void* d_ws, size_t ws_size,
                              hipStream_t stream) {
  const float* x  = (const float*)d_in[0];
  const float* wq = (const float*)d_in[1];
  const float* bq = (const float*)d_in[2];
  const float* wk = (const float*)d_in[3];
  const float* bk = (const float*)d_in[4];
  const float* wv = (const float*)d_in[5];
  const float* bv = (const float*)d_in[6];
  float* out = (float*)d_out;

  unsigned short* ws   = (unsigned short*)d_ws;
  unsigned short* qb   = ws;                   // 8*4096*32  = 1,048,576
  unsigned short* kb   = qb + 1048576;         // 1,048,576
  unsigned short* vT   = kb + 1048576;         // 8*256*4096 = 8,388,608
  unsigned short* xb   = vT + 8388608;         // 8,388,608
  unsigned short* wqkT = xb + 8388608;         // 64*256 = 16,384
  unsigned short* wvT  = wqkT + 16384;         // 256*256 = 65,536

  prep_kernel<<<dim3(2048), dim3(256), 0, stream>>>(x, wq, wk, wv, xb, wqkT, wvT);
  qk_proj_kernel<<<dim3(512), dim3(256), 0, stream>>>(xb, wqkT, bq, bk, qb, kb);
  v_proj_kernel<<<dim3(2048), dim3(256), 0, stream>>>(xb, wvT, bv, vT);
  attn_kernel<<<dim3(512), dim3(256), 0, stream>>>(qb, kb, vT, x, out);
}